// Round 7
// baseline (608.074 us; speedup 1.0000x reference)
//
#include <hip/hip_runtime.h>

#define C_ 96
#define H_ 512
#define W_ 96
#define HW_ 49152        // H_*W_
#define CHW_ 4718592     // C_*HW_
#define PIT 104          // LDS row pitch in f16 elements (208 B)
#define REG 9984         // 96*PIT elements per region
#define TILES 8          // h-tiles per workgroup; 512 wgs = 2/CU exactly

typedef _Float16 f16x8 __attribute__((ext_vector_type(8)));
typedef _Float16 f16x4 __attribute__((ext_vector_type(4)));
typedef _Float16 f16x2 __attribute__((ext_vector_type(2)));
typedef float    f32x4 __attribute__((ext_vector_type(4)));
typedef int      i32x4 __attribute__((ext_vector_type(4)));

#define MFMA16 __builtin_amdgcn_mfma_f32_16x16x32_f16

// LDS-only barrier: order ds ops without draining vmcnt.
#define BAR() do { __builtin_amdgcn_sched_barrier(0); \
                   asm volatile("s_waitcnt lgkmcnt(0)" ::: "memory"); \
                   __builtin_amdgcn_s_barrier(); \
                   __builtin_amdgcn_sched_barrier(0); } while (0)

// Prep 1: fold BN into QKV weights + bias.
__global__ void prep_kernel(const float* __restrict__ wq,
                            const float* __restrict__ gamma,
                            const float* __restrict__ beta,
                            const float* __restrict__ mean,
                            const float* __restrict__ var,
                            const float* __restrict__ qkvb,
                            _Float16* __restrict__ whf,
                            float* __restrict__ bprime)
{
    int i = blockIdx.x * 256 + threadIdx.x;
    if (i < 3 * C_ * C_) {
        int c = i % C_;
        float iv = gamma[c] * rsqrtf(var[c] + 1e-5f);
        whf[i] = (_Float16)(wq[i] * iv);
    }
    if (i < 3 * C_) {
        float acc = qkvb[i];
        for (int c = 0; c < C_; ++c) {
            float iv = gamma[c] * rsqrtf(var[c] + 1e-5f);
            acc += wq[i * C_ + c] * (beta[c] - mean[c] * iv);
        }
        bprime[i] = acc;
    }
}

// Prep 2: atm[c*96+c'] = (W_q'^T W_k')[c'][c],  g0[c] = sum_o b_q'[o]*W_k'[o][c]
__global__ void prep2_kernel(const float* __restrict__ wq,
                             const float* __restrict__ gamma,
                             const float* __restrict__ var,
                             const float* __restrict__ bprime,
                             _Float16* __restrict__ atm,
                             float* __restrict__ g0)
{
    int i = blockIdx.x * 256 + threadIdx.x;
    if (i >= 9216) return;
    int c = i / 96, cp = i % 96;
    float ivc  = gamma[c]  * rsqrtf(var[c]  + 1e-5f);
    float ivcp = gamma[cp] * rsqrtf(var[cp] + 1e-5f);
    float acc = 0.f;
    #pragma unroll 8
    for (int o = 0; o < 96; ++o)
        acc += wq[o * 96 + cp] * wq[(96 + o) * 96 + c];
    atm[c * 96 + cp] = (_Float16)(acc * ivc * ivcp);
    if (cp == 0) {
        float a2 = 0.f;
        #pragma unroll 8
        for (int o = 0; o < 96; ++o)
            a2 += bprime[o] * wq[(96 + o) * 96 + c];
        g0[c] = a2 * ivc;
    }
}

// D-layout -> B-frag exchange (validated R2/R3/R5/R6).
__device__ __forceinline__ void xchg(const f32x4 v[6], float scale,
                                     int q4, int n16, f16x8 fr[3])
{
    int pq[6][2];
    #pragma unroll
    for (int nt = 0; nt < 6; ++nt) {
        #pragma unroll
        for (int jj = 0; jj < 2; ++jj) {
            f16x2 h;
            h[0] = (_Float16)(v[nt][2 * jj] * scale);
            h[1] = (_Float16)(v[nt][2 * jj + 1] * scale);
            pq[nt][jj] = __builtin_bit_cast(int, h);
        }
    }
    const int srcA = ((q4 & 1) << 5) | n16;
    const int srcB = srcA + 16;
    #pragma unroll
    for (int kk = 0; kk < 3; ++kk) {
        const int a0 = __shfl(pq[2 * kk][0], srcA), a1 = __shfl(pq[2 * kk][1], srcA);
        const int a2 = __shfl(pq[2 * kk][0], srcB), a3 = __shfl(pq[2 * kk][1], srcB);
        const int b0 = __shfl(pq[2 * kk + 1][0], srcA), b1 = __shfl(pq[2 * kk + 1][1], srcA);
        const int b2 = __shfl(pq[2 * kk + 1][0], srcB), b3 = __shfl(pq[2 * kk + 1][1], srcB);
        i32x4 u;
        u[0] = (q4 < 2) ? a0 : b0;
        u[1] = (q4 < 2) ? a1 : b1;
        u[2] = (q4 < 2) ? a2 : b2;
        u[3] = (q4 < 2) ? a3 : b3;
        fr[kk] = __builtin_bit_cast(f16x8, u);
    }
}

// Weight-stationary streaming: 512 wgs, 8 h-consecutive tiles each.
// atm A-frags resident in VGPRs; ping-pong LDS (XN+XNT per buffer);
// ONE barrier per tile; residual read back from XNT (f16).
__global__ __launch_bounds__(384, 3) void attn_kernel(
    const float* __restrict__ x,
    const _Float16* __restrict__ whf,
    const _Float16* __restrict__ atm,
    const float* __restrict__ g0,
    const float* __restrict__ bprime,
    float* __restrict__ out)
{
    __shared__ __align__(16) _Float16 smem[4 * REG];   // 79,872 B -> 2 wg/CU

    const int tid  = threadIdx.x;
    const int ws   = tid >> 6;
    const int lane = tid & 63;
    const int q4   = lane >> 4;
    const int n16  = lane & 15;
    const int w0   = 16 * ws + 4 * q4;
    const int qrow = 16 * ws + n16;

    const int wg = blockIdx.x;
    size_t base = (size_t)(wg >> 6) * CHW_ + (size_t)((wg & 63) * TILES) * W_;

    // ---- loop-invariant: atm A-fragments resident (72 VGPRs) ----
    f16x8 atf[3][6];
    #pragma unroll
    for (int kk = 0; kk < 3; ++kk)
        #pragma unroll
        for (int nt = 0; nt < 6; ++nt)
            atf[kk][nt] = *(const f16x8*)(atm + (16 * nt + n16) * 96 + 32 * kk + 8 * q4);

    // ---- stage tile 0 into buffer 0 ----
    {
        f32x4 xr[6];
        #pragma unroll
        for (int t6 = 0; t6 < 6; ++t6)
            xr[t6] = *(const f32x4*)(x + base + (size_t)(16 * t6 + n16) * HW_ + w0);
        #pragma unroll
        for (int t6 = 0; t6 < 6; ++t6) {
            const int c = 16 * t6 + n16;
            f16x4 pk;
            #pragma unroll
            for (int r = 0; r < 4; ++r) pk[r] = (_Float16)xr[t6][r];
            *(f16x4*)(smem + REG + c * PIT + w0) = pk;           // XNT0
            #pragma unroll
            for (int r = 0; r < 4; ++r)
                smem[(w0 + r) * PIT + c] = (_Float16)xr[t6][r];  // XN0
        }
    }
    BAR();

    #pragma unroll 2
    for (int t = 0; t < TILES; ++t) {
        _Float16* XNc  = smem + ((t & 1) ? 2 * REG : 0);
        _Float16* XNTc = XNc + REG;
        _Float16* XNn  = smem + ((t & 1) ? 0 : 2 * REG);
        _Float16* XNTn = XNn + REG;

        // ---- G-pass: G^T[c][q] = atm . xn[q] + g0 (A in registers) ----
        f32x4 gac[6];
        #pragma unroll
        for (int nt = 0; nt < 6; ++nt)
            gac[nt] = *(const f32x4*)(g0 + 16 * nt + 4 * q4);
        #pragma unroll
        for (int kk = 0; kk < 3; ++kk) {
            const f16x8 bq = *(const f16x8*)(XNc + qrow * PIT + 32 * kk + 8 * q4);
            #pragma unroll
            for (int nt = 0; nt < 6; ++nt)
                gac[nt] = MFMA16(atf[kk][nt], bq, gac[nt], 0, 0, 0);
        }
        f16x8 gf[3];
        xchg(gac, 1.0f, q4, n16, gf);

        // ---- S-pass: S^T[k][q] = xn[k] . G[q] ----
        f32x4 sacc[6];
        #pragma unroll
        for (int nt = 0; nt < 6; ++nt) sacc[nt] = f32x4{0.f, 0.f, 0.f, 0.f};
        #pragma unroll
        for (int kk = 0; kk < 3; ++kk) {
            #pragma unroll
            for (int nt = 0; nt < 6; ++nt) {
                const f16x8 a = *(const f16x8*)(XNc + (16 * nt + n16) * PIT + 32 * kk + 8 * q4);
                sacc[nt] = MFMA16(a, gf[kk], sacc[nt], 0, 0, 0);
            }
        }

        // ---- softmax over k (lane owns q-row) ----
        float mr0 = sacc[0][0], mr1 = sacc[0][1], mr2 = sacc[0][2], mr3 = sacc[0][3];
        #pragma unroll
        for (int nt = 1; nt < 6; ++nt) {
            mr0 = fmaxf(mr0, sacc[nt][0]); mr1 = fmaxf(mr1, sacc[nt][1]);
            mr2 = fmaxf(mr2, sacc[nt][2]); mr3 = fmaxf(mr3, sacc[nt][3]);
        }
        float m = fmaxf(fmaxf(mr0, mr1), fmaxf(mr2, mr3));
        m = fmaxf(m, __shfl_xor(m, 16));
        m = fmaxf(m, __shfl_xor(m, 32));
        float sr0 = 0.f, sr1 = 0.f, sr2 = 0.f, sr3 = 0.f;
        #pragma unroll
        for (int nt = 0; nt < 6; ++nt) {
            sacc[nt][0] = __expf(sacc[nt][0] - m); sr0 += sacc[nt][0];
            sacc[nt][1] = __expf(sacc[nt][1] - m); sr1 += sacc[nt][1];
            sacc[nt][2] = __expf(sacc[nt][2] - m); sr2 += sacc[nt][2];
            sacc[nt][3] = __expf(sacc[nt][3] - m); sr3 += sacc[nt][3];
        }
        float s = (sr0 + sr1) + (sr2 + sr3);
        s += __shfl_xor(s, 16);
        s += __shfl_xor(s, 32);
        const float pinv = 1.0f / s;
        f16x8 pa[3];
        xchg(sacc, pinv, q4, n16, pa);

        // ---- issue next-tile x loads (land under Z/O/epilogue) ----
        f32x4 xrn[6];
        if (t < TILES - 1) {
            #pragma unroll
            for (int t6 = 0; t6 < 6; ++t6)
                xrn[t6] = *(const f32x4*)(x + base + W_
                              + (size_t)(16 * t6 + n16) * HW_ + w0);
        }

        // ---- Z-pass: Z^T[c][q] = xn^T[c] . P[q] ----
        f32x4 zac[6];
        #pragma unroll
        for (int nt = 0; nt < 6; ++nt) zac[nt] = f32x4{0.f, 0.f, 0.f, 0.f};
        #pragma unroll
        for (int kk = 0; kk < 3; ++kk) {
            #pragma unroll
            for (int nt = 0; nt < 6; ++nt) {
                const f16x8 a = *(const f16x8*)(XNTc + (16 * nt + n16) * PIT + 32 * kk + 8 * q4);
                zac[nt] = MFMA16(a, pa[kk], zac[nt], 0, 0, 0);
            }
        }
        f16x8 zf[3];
        xchg(zac, 1.0f, q4, n16, zf);

        // ---- O-pass: O^T[cv][q] = Wv'[cv] . Z[q] + bv (whf L2-hot, JIT) ----
        f32x4 oacc[6];
        #pragma unroll
        for (int ot = 0; ot < 6; ++ot)
            oacc[ot] = *(const f32x4*)(bprime + 192 + 16 * ot + 4 * q4);
        #pragma unroll
        for (int kk = 0; kk < 3; ++kk) {
            f16x8 wv[6];
            #pragma unroll
            for (int ot = 0; ot < 6; ++ot)
                wv[ot] = *(const f16x8*)(whf + (192 + 16 * ot + n16) * 96 + 32 * kk + 8 * q4);
            #pragma unroll
            for (int ot = 0; ot < 6; ++ot)
                oacc[ot] = MFMA16(wv[ot], zf[kk], oacc[ot], 0, 0, 0);
        }

        // ---- epilogue: residual from XNT (f16), store ----
        #pragma unroll
        for (int ot = 0; ot < 6; ++ot) {
            #pragma unroll
            for (int r = 0; r < 4; ++r) {
                const float xv = (float)XNTc[(16 * ot + 4 * q4 + r) * PIT + qrow];
                out[base + (size_t)(16 * ot + 4 * q4 + r) * HW_ + qrow] =
                    oacc[ot][r] + xv;
            }
        }

        // ---- stage next tile into the other buffer; one BAR per tile ----
        if (t < TILES - 1) {
            #pragma unroll
            for (int t6 = 0; t6 < 6; ++t6) {
                const int c = 16 * t6 + n16;
                f16x4 pk;
                #pragma unroll
                for (int r = 0; r < 4; ++r) pk[r] = (_Float16)xrn[t6][r];
                *(f16x4*)(XNTn + c * PIT + w0) = pk;
                #pragma unroll
                for (int r = 0; r < 4; ++r)
                    XNn[(w0 + r) * PIT + c] = (_Float16)xrn[t6][r];
            }
            base += W_;
            BAR();
        }
    }
}

extern "C" void kernel_launch(void* const* d_in, const int* in_sizes, int n_in,
                              void* d_out, int out_size, void* d_ws, size_t ws_size,
                              hipStream_t stream)
{
    const float* x     = (const float*)d_in[0];
    const float* gamma = (const float*)d_in[1];
    const float* beta  = (const float*)d_in[2];
    const float* mean  = (const float*)d_in[3];
    const float* var   = (const float*)d_in[4];
    const float* qkvw  = (const float*)d_in[5];
    const float* qkvb  = (const float*)d_in[6];
    float* out = (float*)d_out;

    _Float16* whf    = (_Float16*)d_ws;                     // [0, 55296)
    float*    bprime = (float*)((char*)d_ws + 55296);       // [55296, 56448)
    _Float16* atm    = (_Float16*)((char*)d_ws + 56448);    // [56448, 74880)
    float*    g0v    = (float*)((char*)d_ws + 74880);       // [74880, 75264)

    prep_kernel<<<108, 256, 0, stream>>>(qkvw, gamma, beta, mean, var, qkvb, whf, bprime);
    prep2_kernel<<<36, 256, 0, stream>>>(qkvw, gamma, var, bprime, atm, g0v);
    attn_kernel<<<512, 384, 0, stream>>>(x, whf, atm, g0v, bprime, out);
}

// Round 8
// 325.202 us; speedup vs baseline: 1.8698x; 1.8698x over previous
//
#include <hip/hip_runtime.h>

#define C_ 96
#define H_ 512
#define W_ 96
#define HW_ 49152        // H_*W_
#define CHW_ 4718592     // C_*HW_
#define PIT 104          // LDS row pitch in f16 elements (208 B, 16B-aligned rows)
#define REG 9984         // 96*PIT elements per region

typedef _Float16 f16x8 __attribute__((ext_vector_type(8)));
typedef _Float16 f16x4 __attribute__((ext_vector_type(4)));
typedef _Float16 f16x2 __attribute__((ext_vector_type(2)));
typedef float    f32x4 __attribute__((ext_vector_type(4)));
typedef int      i32x4 __attribute__((ext_vector_type(4)));

#define MFMA16 __builtin_amdgcn_mfma_f32_16x16x32_f16

// LDS-only barrier: order ds ops without draining vmcnt.
#define BAR() do { __builtin_amdgcn_sched_barrier(0); \
                   asm volatile("s_waitcnt lgkmcnt(0)" ::: "memory"); \
                   __builtin_amdgcn_s_barrier(); \
                   __builtin_amdgcn_sched_barrier(0); } while (0)

// Prep 1: whf = BN-folded QKV weights (f16); inv/shift per channel.
__global__ void prep_kernel(const float* __restrict__ wq,
                            const float* __restrict__ gamma,
                            const float* __restrict__ beta,
                            const float* __restrict__ mean,
                            const float* __restrict__ var,
                            _Float16* __restrict__ whf,
                            float* __restrict__ inv,
                            float* __restrict__ shift)
{
    int i = blockIdx.x * 256 + threadIdx.x;
    if (i < 3 * C_ * C_) {
        int c = i % C_;
        float iv = gamma[c] * rsqrtf(var[c] + 1e-5f);
        whf[i] = (_Float16)(wq[i] * iv);
    }
    if (i < C_) {
        float iv = gamma[i] * rsqrtf(var[i] + 1e-5f);
        inv[i]   = iv;
        shift[i] = beta[i] - mean[i] * iv;
    }
}

// Prep 1b: bprime[o] = qkv_b[o] + sum_c W[o][c]*shift[c].  One wave per o.
__global__ void prep_bias(const float* __restrict__ wq,
                          const float* __restrict__ qkvb,
                          const float* __restrict__ shift,
                          float* __restrict__ bprime)
{
    const int o = (blockIdx.x * 256 + threadIdx.x) >> 6;
    const int l = threadIdx.x & 63;
    if (o >= 3 * C_) return;
    float p = wq[o * C_ + l] * shift[l];
    if (l < 32) p += wq[o * C_ + 64 + l] * shift[64 + l];
    #pragma unroll
    for (int d = 32; d >= 1; d >>= 1) p += __shfl_xor(p, d);
    if (l == 0) bprime[o] = p + qkvb[o];
}

// Prep 2: one block per c.  atm[c*96+cp] = sum_o Wq[o][cp]Wk[o][c] * ivc*ivcp
//         g0[c] = (sum_o bprime_q[o]*Wk[o][c]) * ivc   (wave 1)
__global__ void prep2_kernel(const float* __restrict__ wq,
                             const float* __restrict__ inv,
                             const float* __restrict__ bprime,
                             _Float16* __restrict__ atm,
                             float* __restrict__ g0)
{
    const int c = blockIdx.x;
    const int t = threadIdx.x;
    __shared__ float ldsk[C_];
    if (t < C_) ldsk[t] = wq[(C_ + t) * C_ + c];   // W_k[o=t][c]
    __syncthreads();
    const float ivc = inv[c];
    if (t < C_) {
        float acc = 0.f;
        #pragma unroll 8
        for (int o = 0; o < C_; ++o)
            acc += wq[o * C_ + t] * ldsk[o];
        atm[c * C_ + t] = (_Float16)(acc * ivc * inv[t]);
    }
    if (t >= 64) {        // wave 1: g0[c]
        const int l = t - 64;
        float p = bprime[l] * ldsk[l];
        if (l < 32) p += bprime[64 + l] * ldsk[64 + l];
        #pragma unroll
        for (int d = 32; d >= 1; d >>= 1) p += __shfl_xor(p, d);
        if (l == 0) g0[c] = p * ivc;
    }
}

// D-layout -> B-frag exchange (validated R2/R3).
__device__ __forceinline__ void xchg(const f32x4 v[6], float scale,
                                     int q4, int n16, f16x8 fr[3])
{
    int pq[6][2];
    #pragma unroll
    for (int nt = 0; nt < 6; ++nt) {
        #pragma unroll
        for (int jj = 0; jj < 2; ++jj) {
            f16x2 h;
            h[0] = (_Float16)(v[nt][2 * jj] * scale);
            h[1] = (_Float16)(v[nt][2 * jj + 1] * scale);
            pq[nt][jj] = __builtin_bit_cast(int, h);
        }
    }
    const int srcA = ((q4 & 1) << 5) | n16;
    const int srcB = srcA + 16;
    #pragma unroll
    for (int kk = 0; kk < 3; ++kk) {
        const int a0 = __shfl(pq[2 * kk][0], srcA), a1 = __shfl(pq[2 * kk][1], srcA);
        const int a2 = __shfl(pq[2 * kk][0], srcB), a3 = __shfl(pq[2 * kk][1], srcB);
        const int b0 = __shfl(pq[2 * kk + 1][0], srcA), b1 = __shfl(pq[2 * kk + 1][1], srcA);
        const int b2 = __shfl(pq[2 * kk + 1][0], srcB), b3 = __shfl(pq[2 * kk + 1][1], srcB);
        i32x4 u;
        u[0] = (q4 < 2) ? a0 : b0;
        u[1] = (q4 < 2) ? a1 : b1;
        u[2] = (q4 < 2) ? a2 : b2;
        u[3] = (q4 < 2) ? a3 : b3;
        fr[kk] = __builtin_bit_cast(f16x8, u);
    }
}

// One wg per (b,h). 6 waves, ONE barrier, 2 LDS regions (39,936 B -> 3 wg/CU).
// G = xn*A + g0 ; S = xn*G^T ; softmax ; Z = P*xn ; O = Z*Wv'^T + bv ; +x(LDS)
__global__ __launch_bounds__(384, 5) void attn_kernel(
    const float* __restrict__ x,
    const _Float16* __restrict__ whf,
    const _Float16* __restrict__ atm,
    const float* __restrict__ g0,
    const float* __restrict__ bprime,
    float* __restrict__ out)
{
    __shared__ __align__(16) _Float16 smem[2 * REG];
    _Float16* XN  = smem;           // x[w][c] (f16)
    _Float16* XNT = smem + REG;     // x^T[c][w] (f16) — also the residual source

    const int tid  = threadIdx.x;
    const int ws   = tid >> 6;
    const int lane = tid & 63;
    const int q4   = lane >> 4;
    const int n16  = lane & 15;
    const int w0   = 16 * ws + 4 * q4;
    const int qrow = 16 * ws + n16;   // this lane's q row

    const int bh = blockIdx.x;
    const size_t base = (size_t)(bh >> 9) * CHW_ + (size_t)(bh & 511) * W_;

    // ---- stage: x -> XN[w][c] (b16) and XNT[c][w] (b64) ----
    {
        f32x4 xr[6];
        #pragma unroll
        for (int t = 0; t < 6; ++t)
            xr[t] = *(const f32x4*)(x + base + (size_t)(16 * t + n16) * HW_ + w0);
        #pragma unroll
        for (int t = 0; t < 6; ++t) {
            const int c = 16 * t + n16;
            f16x4 pk;
            #pragma unroll
            for (int r = 0; r < 4; ++r) pk[r] = (_Float16)xr[t][r];
            *(f16x4*)(XNT + c * PIT + w0) = pk;
            #pragma unroll
            for (int r = 0; r < 4; ++r)
                XN[(w0 + r) * PIT + c] = (_Float16)xr[t][r];
        }
    }
    BAR();   // the only barrier

    // ---- G-pass: G^T[c][q] = sum_c' atm[c][c'] x[q][c'] + g0[c] ----
    f32x4 gac[6];
    #pragma unroll
    for (int nt = 0; nt < 6; ++nt)
        gac[nt] = *(const f32x4*)(g0 + 16 * nt + 4 * q4);
    #pragma unroll
    for (int kk = 0; kk < 3; ++kk) {
        const f16x8 bfr = *(const f16x8*)(XN + qrow * PIT + 32 * kk + 8 * q4);
        #pragma unroll
        for (int nt = 0; nt < 6; ++nt) {
            const f16x8 afr = *(const f16x8*)(atm + (16 * nt + n16) * 96 + 32 * kk + 8 * q4);
            gac[nt] = MFMA16(afr, bfr, gac[nt], 0, 0, 0);
        }
    }
    f16x8 gf[3];
    xchg(gac, 1.0f, q4, n16, gf);

    // ---- S-pass: S^T[k][q] = x[k][:] . G[q][:] ----
    f32x4 sacc[6];
    #pragma unroll
    for (int nt = 0; nt < 6; ++nt) sacc[nt] = f32x4{0.f, 0.f, 0.f, 0.f};
    #pragma unroll
    for (int kk = 0; kk < 3; ++kk) {
        #pragma unroll
        for (int nt = 0; nt < 6; ++nt) {
            const f16x8 afr = *(const f16x8*)(XN + (16 * nt + n16) * PIT + 32 * kk + 8 * q4);
            sacc[nt] = MFMA16(afr, gf[kk], sacc[nt], 0, 0, 0);
        }
    }

    // ---- softmax over k (lane owns its q-row; reduce across q4 pair) ----
    float mr0 = sacc[0][0], mr1 = sacc[0][1], mr2 = sacc[0][2], mr3 = sacc[0][3];
    #pragma unroll
    for (int nt = 1; nt < 6; ++nt) {
        mr0 = fmaxf(mr0, sacc[nt][0]); mr1 = fmaxf(mr1, sacc[nt][1]);
        mr2 = fmaxf(mr2, sacc[nt][2]); mr3 = fmaxf(mr3, sacc[nt][3]);
    }
    float m = fmaxf(fmaxf(mr0, mr1), fmaxf(mr2, mr3));
    m = fmaxf(m, __shfl_xor(m, 16));
    m = fmaxf(m, __shfl_xor(m, 32));
    float sr0 = 0.f, sr1 = 0.f, sr2 = 0.f, sr3 = 0.f;
    #pragma unroll
    for (int nt = 0; nt < 6; ++nt) {
        sacc[nt][0] = __expf(sacc[nt][0] - m); sr0 += sacc[nt][0];
        sacc[nt][1] = __expf(sacc[nt][1] - m); sr1 += sacc[nt][1];
        sacc[nt][2] = __expf(sacc[nt][2] - m); sr2 += sacc[nt][2];
        sacc[nt][3] = __expf(sacc[nt][3] - m); sr3 += sacc[nt][3];
    }
    float s = (sr0 + sr1) + (sr2 + sr3);
    s += __shfl_xor(s, 16);
    s += __shfl_xor(s, 32);
    const float pinv = 1.0f / s;

    f16x8 pa[3];
    xchg(sacc, pinv, q4, n16, pa);   // pa[kk] = P[own q][k = 32kk+8q4+e]

    // ---- Z-pass: Z^T[c][q] = x^T[c][:] . P[q][:] ----
    f32x4 zac[6];
    #pragma unroll
    for (int nt = 0; nt < 6; ++nt) zac[nt] = f32x4{0.f, 0.f, 0.f, 0.f};
    #pragma unroll
    for (int kk = 0; kk < 3; ++kk) {
        #pragma unroll
        for (int nt = 0; nt < 6; ++nt) {
            const f16x8 afr = *(const f16x8*)(XNT + (16 * nt + n16) * PIT + 32 * kk + 8 * q4);
            zac[nt] = MFMA16(afr, pa[kk], zac[nt], 0, 0, 0);
        }
    }
    f16x8 zf[3];
    xchg(zac, 1.0f, q4, n16, zf);

    // ---- O-pass: O^T[cv][q] = Wv'[cv][:] . Z[q][:] + bv[cv] ----
    f32x4 oacc[6];
    #pragma unroll
    for (int ot = 0; ot < 6; ++ot)
        oacc[ot] = *(const f32x4*)(bprime + 192 + 16 * ot + 4 * q4);
    #pragma unroll
    for (int kk = 0; kk < 3; ++kk) {
        #pragma unroll
        for (int ot = 0; ot < 6; ++ot) {
            const f16x8 afr = *(const f16x8*)(whf + (192 + 16 * ot + n16) * 96 + 32 * kk + 8 * q4);
            oacc[ot] = MFMA16(afr, zf[kk], oacc[ot], 0, 0, 0);
        }
    }

    // ---- epilogue: residual from XNT (f16 copy of x), store ----
    #pragma unroll
    for (int ot = 0; ot < 6; ++ot) {
        #pragma unroll
        for (int r = 0; r < 4; ++r) {
            const float xv = (float)XNT[(16 * ot + 4 * q4 + r) * PIT + qrow];
            out[base + (size_t)(16 * ot + 4 * q4 + r) * HW_ + qrow] =
                oacc[ot][r] + xv;
        }
    }
}

extern "C" void kernel_launch(void* const* d_in, const int* in_sizes, int n_in,
                              void* d_out, int out_size, void* d_ws, size_t ws_size,
                              hipStream_t stream)
{
    const float* x     = (const float*)d_in[0];
    const float* gamma = (const float*)d_in[1];
    const float* beta  = (const float*)d_in[2];
    const float* mean  = (const float*)d_in[3];
    const float* var   = (const float*)d_in[4];
    const float* qkvw  = (const float*)d_in[5];
    const float* qkvb  = (const float*)d_in[6];
    float* out = (float*)d_out;

    _Float16* whf    = (_Float16*)d_ws;                     // [0, 55296)
    float*    bprime = (float*)((char*)d_ws + 55296);       // [55296, 56448)
    _Float16* atm    = (_Float16*)((char*)d_ws + 56448);    // [56448, 74880)
    float*    g0v    = (float*)((char*)d_ws + 74880);       // [74880, 75264)
    float*    inv    = (float*)((char*)d_ws + 75264);       // [75264, 75648)
    float*    shf    = (float*)((char*)d_ws + 75648);       // [75648, 76032)

    prep_kernel<<<108, 256, 0, stream>>>(qkvw, gamma, beta, mean, var, whf, inv, shf);
    prep_bias <<<72, 256, 0, stream>>>(qkvw, qkvb, shf, bprime);
    prep2_kernel<<<96, 128, 0, stream>>>(qkvw, inv, bprime, atm, g0v);
    attn_kernel<<<4096, 384, 0, stream>>>(x, whf, atm, g0v, bprime, out);
}

// Round 9
// 320.811 us; speedup vs baseline: 1.8954x; 1.0137x over previous
//
#include <hip/hip_runtime.h>

#define C_ 96
#define H_ 512
#define W_ 96
#define HW_ 49152        // H_*W_
#define CHW_ 4718592     // C_*HW_
#define PIT 104          // LDS row pitch in f16 elements (208 B, 16B-aligned rows)
#define REG 9984         // 96*PIT elements per region

typedef _Float16 f16x8 __attribute__((ext_vector_type(8)));
typedef _Float16 f16x4 __attribute__((ext_vector_type(4)));
typedef _Float16 f16x2 __attribute__((ext_vector_type(2)));
typedef float    f32x4 __attribute__((ext_vector_type(4)));
typedef int      i32x4 __attribute__((ext_vector_type(4)));

#define MFMA16 __builtin_amdgcn_mfma_f32_16x16x32_f16

// LDS-only barrier: order ds ops without draining vmcnt.
#define BAR() do { __builtin_amdgcn_sched_barrier(0); \
                   asm volatile("s_waitcnt lgkmcnt(0)" ::: "memory"); \
                   __builtin_amdgcn_s_barrier(); \
                   __builtin_amdgcn_sched_barrier(0); } while (0)

__device__ __forceinline__ float bn_inv(const float* g, const float* v, int c) {
    return g[c] * rsqrtf(v[c] + 1e-5f);
}

// Prep A: blocks 0-107: whf = BN-folded QKV weights (f16).
//         blocks 108-179: bprime[o] = qkv_b[o] + sum_c W[o][c]*shift[c] (1 wave/o).
__global__ void prepA_kernel(const float* __restrict__ wq,
                             const float* __restrict__ gamma,
                             const float* __restrict__ beta,
                             const float* __restrict__ mean,
                             const float* __restrict__ var,
                             const float* __restrict__ qkvb,
                             _Float16* __restrict__ whf,
                             float* __restrict__ bprime)
{
    if (blockIdx.x < 108) {
        int i = blockIdx.x * 256 + threadIdx.x;
        if (i < 3 * C_ * C_) {
            int c = i % C_;
            whf[i] = (_Float16)(wq[i] * bn_inv(gamma, var, c));
        }
    } else {
        const int j = (blockIdx.x - 108) * 256 + threadIdx.x;
        const int o = j >> 6;
        const int l = j & 63;
        if (o >= 3 * C_) return;
        const float sh0 = beta[l] - mean[l] * bn_inv(gamma, var, l);
        float p = wq[o * C_ + l] * sh0;
        if (l < 32) {
            const float sh1 = beta[64 + l] - mean[64 + l] * bn_inv(gamma, var, 64 + l);
            p += wq[o * C_ + 64 + l] * sh1;
        }
        #pragma unroll
        for (int d = 32; d >= 1; d >>= 1) p += __shfl_xor(p, d);
        if (l == 0) bprime[o] = p + qkvb[o];
    }
}

// Prep 2: one block (128 thr) per c.
//   atm[c*96+t] = (sum_o Wq[o][t] Wk[o][c]) * ivc*ivt
//   g0[c] = (sum_o bprime_q[o] Wk[o][c]) * ivc      (wave 1)
__global__ void prep2_kernel(const float* __restrict__ wq,
                             const float* __restrict__ gamma,
                             const float* __restrict__ var,
                             const float* __restrict__ bprime,
                             _Float16* __restrict__ atm,
                             float* __restrict__ g0)
{
    const int c = blockIdx.x;
    const int t = threadIdx.x;
    __shared__ float ldsk[C_];
    if (t < C_) ldsk[t] = wq[(C_ + t) * C_ + c];   // W_k[o=t][c]
    __syncthreads();
    const float ivc = bn_inv(gamma, var, c);
    if (t < C_) {
        float acc = 0.f;
        #pragma unroll 8
        for (int o = 0; o < C_; ++o)
            acc += wq[o * C_ + t] * ldsk[o];
        atm[c * C_ + t] = (_Float16)(acc * ivc * bn_inv(gamma, var, t));
    }
    if (t >= 64) {        // wave 1: g0[c]
        const int l = t - 64;
        float p = bprime[l] * ldsk[l];
        if (l < 32) p += bprime[64 + l] * ldsk[64 + l];
        #pragma unroll
        for (int d = 32; d >= 1; d >>= 1) p += __shfl_xor(p, d);
        if (l == 0) g0[c] = p * ivc;
    }
}

// D-layout -> B-frag exchange (validated R2/R3/R8).
__device__ __forceinline__ void xchg(const f32x4 v[6], float scale,
                                     int q4, int n16, f16x8 fr[3])
{
    int pq[6][2];
    #pragma unroll
    for (int nt = 0; nt < 6; ++nt) {
        #pragma unroll
        for (int jj = 0; jj < 2; ++jj) {
            f16x2 h;
            h[0] = (_Float16)(v[nt][2 * jj] * scale);
            h[1] = (_Float16)(v[nt][2 * jj + 1] * scale);
            pq[nt][jj] = __builtin_bit_cast(int, h);
        }
    }
    const int srcA = ((q4 & 1) << 5) | n16;
    const int srcB = srcA + 16;
    #pragma unroll
    for (int kk = 0; kk < 3; ++kk) {
        const int a0 = __shfl(pq[2 * kk][0], srcA), a1 = __shfl(pq[2 * kk][1], srcA);
        const int a2 = __shfl(pq[2 * kk][0], srcB), a3 = __shfl(pq[2 * kk][1], srcB);
        const int b0 = __shfl(pq[2 * kk + 1][0], srcA), b1 = __shfl(pq[2 * kk + 1][1], srcA);
        const int b2 = __shfl(pq[2 * kk + 1][0], srcB), b3 = __shfl(pq[2 * kk + 1][1], srcB);
        i32x4 u;
        u[0] = (q4 < 2) ? a0 : b0;
        u[1] = (q4 < 2) ? a1 : b1;
        u[2] = (q4 < 2) ? a2 : b2;
        u[3] = (q4 < 2) ? a3 : b3;
        fr[kk] = __builtin_bit_cast(f16x8, u);
    }
}

// One wg per (b,h). 6 waves, ONE barrier, 4 LDS regions (79,872 B -> 2 wg/CU):
//   XN  = x[w][c], XNT = x^T[c][w]  (f16; XN also the residual source)
//   WA  = atm staged, WV = whf_v staged  (read from LDS, not global — kills
//         the 216 KB/wg of scattered global weight re-reads, 6x per wg)
// G = xn*A + g0 ; S = xn*G^T ; softmax ; Z = P*xn ; O = Z*Wv'^T + bv ; +x(LDS)
__global__ __launch_bounds__(384, 3) void attn_kernel(
    const float* __restrict__ x,
    const _Float16* __restrict__ whf,
    const _Float16* __restrict__ atm,
    const float* __restrict__ g0,
    const float* __restrict__ bprime,
    float* __restrict__ out)
{
    __shared__ __align__(16) _Float16 smem[4 * REG];
    _Float16* XN  = smem;             // x[w][c]
    _Float16* XNT = smem + REG;       // x^T[c][w]
    _Float16* WA  = smem + 2 * REG;   // atm rows, pitch PIT
    _Float16* WV  = smem + 3 * REG;   // whf_v rows, pitch PIT

    const int tid  = threadIdx.x;
    const int ws   = tid >> 6;
    const int lane = tid & 63;
    const int q4   = lane >> 4;
    const int n16  = lane & 15;
    const int w0   = 16 * ws + 4 * q4;
    const int qrow = 16 * ws + n16;   // this lane's q row

    const int bh = blockIdx.x;
    const size_t base = (size_t)(bh >> 9) * CHW_ + (size_t)(bh & 511) * W_;

    // ---- cooperative weight staging: 192 rows x 192 B, coalesced 16B ----
    #pragma unroll
    for (int i = 0; i < 6; ++i) {
        const int idx = i * 384 + tid;        // 0..2303
        const int row = idx / 12, seg = idx % 12;
        const f16x8 v = (row < 96)
            ? *(const f16x8*)(atm + row * 96 + seg * 8)
            : *(const f16x8*)(whf + (96 + row) * 96 + seg * 8);  // (192+(row-96))*96
        _Float16* dst = (row < 96) ? (WA + row * PIT) : (WV + (row - 96) * PIT);
        *(f16x8*)(dst + seg * 8) = v;
    }

    // ---- stage: x -> XN[w][c] (b16) and XNT[c][w] (b64) ----
    {
        f32x4 xr[6];
        #pragma unroll
        for (int t = 0; t < 6; ++t)
            xr[t] = *(const f32x4*)(x + base + (size_t)(16 * t + n16) * HW_ + w0);
        #pragma unroll
        for (int t = 0; t < 6; ++t) {
            const int c = 16 * t + n16;
            f16x4 pk;
            #pragma unroll
            for (int r = 0; r < 4; ++r) pk[r] = (_Float16)xr[t][r];
            *(f16x4*)(XNT + c * PIT + w0) = pk;
            #pragma unroll
            for (int r = 0; r < 4; ++r)
                XN[(w0 + r) * PIT + c] = (_Float16)xr[t][r];
        }
    }
    BAR();   // the only barrier (covers weights + x staging)

    // ---- G-pass: G^T[c][q] = sum_c' atm[c][c'] x[q][c'] + g0[c] ----
    f32x4 gac[6];
    #pragma unroll
    for (int nt = 0; nt < 6; ++nt)
        gac[nt] = *(const f32x4*)(g0 + 16 * nt + 4 * q4);
    __builtin_amdgcn_s_setprio(1);
    #pragma unroll
    for (int kk = 0; kk < 3; ++kk) {
        const f16x8 bfr = *(const f16x8*)(XN + qrow * PIT + 32 * kk + 8 * q4);
        #pragma unroll
        for (int nt = 0; nt < 6; ++nt) {
            const f16x8 afr = *(const f16x8*)(WA + (16 * nt + n16) * PIT + 32 * kk + 8 * q4);
            gac[nt] = MFMA16(afr, bfr, gac[nt], 0, 0, 0);
        }
    }
    __builtin_amdgcn_s_setprio(0);
    f16x8 gf[3];
    xchg(gac, 1.0f, q4, n16, gf);

    // ---- S-pass: S^T[k][q] = x[k][:] . G[q][:] ----
    f32x4 sacc[6];
    #pragma unroll
    for (int nt = 0; nt < 6; ++nt) sacc[nt] = f32x4{0.f, 0.f, 0.f, 0.f};
    __builtin_amdgcn_s_setprio(1);
    #pragma unroll
    for (int kk = 0; kk < 3; ++kk) {
        #pragma unroll
        for (int nt = 0; nt < 6; ++nt) {
            const f16x8 afr = *(const f16x8*)(XN + (16 * nt + n16) * PIT + 32 * kk + 8 * q4);
            sacc[nt] = MFMA16(afr, gf[kk], sacc[nt], 0, 0, 0);
        }
    }
    __builtin_amdgcn_s_setprio(0);

    // ---- softmax over k (lane owns its q-row; reduce across q4 pair) ----
    float mr0 = sacc[0][0], mr1 = sacc[0][1], mr2 = sacc[0][2], mr3 = sacc[0][3];
    #pragma unroll
    for (int nt = 1; nt < 6; ++nt) {
        mr0 = fmaxf(mr0, sacc[nt][0]); mr1 = fmaxf(mr1, sacc[nt][1]);
        mr2 = fmaxf(mr2, sacc[nt][2]); mr3 = fmaxf(mr3, sacc[nt][3]);
    }
    float m = fmaxf(fmaxf(mr0, mr1), fmaxf(mr2, mr3));
    m = fmaxf(m, __shfl_xor(m, 16));
    m = fmaxf(m, __shfl_xor(m, 32));
    float sr0 = 0.f, sr1 = 0.f, sr2 = 0.f, sr3 = 0.f;
    #pragma unroll
    for (int nt = 0; nt < 6; ++nt) {
        sacc[nt][0] = __expf(sacc[nt][0] - m); sr0 += sacc[nt][0];
        sacc[nt][1] = __expf(sacc[nt][1] - m); sr1 += sacc[nt][1];
        sacc[nt][2] = __expf(sacc[nt][2] - m); sr2 += sacc[nt][2];
        sacc[nt][3] = __expf(sacc[nt][3] - m); sr3 += sacc[nt][3];
    }
    float s = (sr0 + sr1) + (sr2 + sr3);
    s += __shfl_xor(s, 16);
    s += __shfl_xor(s, 32);
    const float pinv = 1.0f / s;

    f16x8 pa[3];
    xchg(sacc, pinv, q4, n16, pa);   // pa[kk] = P[own q][k = 32kk+8q4+e]

    // ---- Z-pass: Z^T[c][q] = x^T[c][:] . P[q][:] ----
    f32x4 zac[6];
    #pragma unroll
    for (int nt = 0; nt < 6; ++nt) zac[nt] = f32x4{0.f, 0.f, 0.f, 0.f};
    __builtin_amdgcn_s_setprio(1);
    #pragma unroll
    for (int kk = 0; kk < 3; ++kk) {
        #pragma unroll
        for (int nt = 0; nt < 6; ++nt) {
            const f16x8 afr = *(const f16x8*)(XNT + (16 * nt + n16) * PIT + 32 * kk + 8 * q4);
            zac[nt] = MFMA16(afr, pa[kk], zac[nt], 0, 0, 0);
        }
    }
    __builtin_amdgcn_s_setprio(0);
    f16x8 zf[3];
    xchg(zac, 1.0f, q4, n16, zf);

    // ---- O-pass: O^T[cv][q] = Wv'[cv][:] . Z[q][:] + bv[cv] ----
    f32x4 oacc[6];
    #pragma unroll
    for (int ot = 0; ot < 6; ++ot)
        oacc[ot] = *(const f32x4*)(bprime + 192 + 16 * ot + 4 * q4);
    __builtin_amdgcn_s_setprio(1);
    #pragma unroll
    for (int kk = 0; kk < 3; ++kk) {
        #pragma unroll
        for (int ot = 0; ot < 6; ++ot) {
            const f16x8 afr = *(const f16x8*)(WV + (16 * ot + n16) * PIT + 32 * kk + 8 * q4);
            oacc[ot] = MFMA16(afr, zf[kk], oacc[ot], 0, 0, 0);
        }
    }
    __builtin_amdgcn_s_setprio(0);

    // ---- epilogue: residual x[c][qrow] = XN[qrow][c] (b64 reads), store ----
    #pragma unroll
    for (int ot = 0; ot < 6; ++ot) {
        const f16x4 xv4 = *(const f16x4*)(XN + qrow * PIT + 16 * ot + 4 * q4);
        #pragma unroll
        for (int r = 0; r < 4; ++r)
            out[base + (size_t)(16 * ot + 4 * q4 + r) * HW_ + qrow] =
                oacc[ot][r] + (float)xv4[r];
    }
}

extern "C" void kernel_launch(void* const* d_in, const int* in_sizes, int n_in,
                              void* d_out, int out_size, void* d_ws, size_t ws_size,
                              hipStream_t stream)
{
    const float* x     = (const float*)d_in[0];
    const float* gamma = (const float*)d_in[1];
    const float* beta  = (const float*)d_in[2];
    const float* mean  = (const float*)d_in[3];
    const float* var   = (const float*)d_in[4];
    const float* qkvw  = (const float*)d_in[5];
    const float* qkvb  = (const float*)d_in[6];
    float* out = (float*)d_out;

    _Float16* whf    = (_Float16*)d_ws;                     // [0, 55296)
    float*    bprime = (float*)((char*)d_ws + 55296);       // [55296, 56448)
    _Float16* atm    = (_Float16*)((char*)d_ws + 56448);    // [56448, 74880)
    float*    g0v    = (float*)((char*)d_ws + 74880);       // [74880, 75264)

    prepA_kernel<<<180, 256, 0, stream>>>(qkvw, gamma, beta, mean, var, qkvb, whf, bprime);
    prep2_kernel<<<96, 128, 0, stream>>>(qkvw, gamma, var, bprime, atm, g0v);
    attn_kernel<<<4096, 384, 0, stream>>>(x, whf, atm, g0v, bprime, out);
}